// Round 15
// baseline (53.020 us; speedup 1.0000x reference)
//
#include <hip/hip_runtime.h>
#include <hip/hip_bf16.h>
#include <math.h>

#define N_NODES 2048
#define IN_F    1024
#define NH      8
#define HF      32
#define OUTF    256   // NH*HF
#define LOG2E   1.4426950408889634f

typedef __attribute__((ext_vector_type(8))) short short8;
typedef __attribute__((ext_vector_type(4))) short short4v;
typedef __attribute__((ext_vector_type(4))) float f32x4;

__device__ __forceinline__ short f2bf(float x) {   // fp32 -> bf16 bits, RNE
  unsigned u = __float_as_uint(x);
  return (short)((u + 0x7FFFu + ((u >> 16) & 1u)) >> 16);
}
__device__ __forceinline__ float bf2f(short b) {
  return __uint_as_float(((unsigned)(unsigned short)b) << 16);
}
__device__ __forceinline__ float fexp2(float x) {  // native v_exp_f32 (2^x)
#if __has_builtin(__builtin_amdgcn_exp2f)
  return __builtin_amdgcn_exp2f(x);
#else
  return exp2f(x);
#endif
}

// ---------------- Kernel 1: prep — W->bf16 hi/lo (T), pack adj bits --------
__global__ __launch_bounds__(256)
void prep_kernel(const int* __restrict__ adj, const float* __restrict__ W,
                 short* __restrict__ wt_hi, short* __restrict__ wt_lo,
                 unsigned* __restrict__ bits) {
  const int T = blockIdx.x * 256 + threadIdx.x;   // 0 .. 131071
  if (T < (OUTF * IN_F / 8)) {
    // W: transpose + split. Lanes sweep n -> coalesced reads of W rows.
    const int kgrp = T >> 8, n = T & 255;      // 128 k-groups x 256 n
    #pragma unroll
    for (int j = 0; j < 8; ++j) {
      const float x = W[(kgrp * 8 + j) * OUTF + n];
      const short hb = f2bf(x);
      wt_hi[n * IN_F + kgrp * 8 + j] = hb;
      wt_lo[n * IN_F + kgrp * 8 + j] = f2bf(x - bf2f(hb));
    }
  }
  {      // 131072 bit words, one per thread
    const int4* p = (const int4*)(adj + (T >> 6) * N_NODES + (T & 63) * 32);
    unsigned wbits = 0;
    #pragma unroll
    for (int v = 0; v < 8; ++v) {
      const int4 x = p[v];
      wbits |= (x.x != 0 ? 1u : 0u) << (4 * v + 0);
      wbits |= (x.y != 0 ? 1u : 0u) << (4 * v + 1);
      wbits |= (x.z != 0 ? 1u : 0u) << (4 * v + 2);
      wbits |= (x.w != 0 ? 1u : 0u) << (4 * v + 3);
    }
    bits[T] = wbits;
  }
}

// ---------------- Kernel 2: g = h@W (MFMA, in-block K-split 2) + scores ----
// R12-proven shape: 256 blocks x 8 waves. Wave = 16 rows x 1 head x K-half;
// K-halves merge through LDS. h read DIRECTLY as fp32, converted in-register
// (single bf16 rounding, identical numerics to the old h_hi path).
__global__ __launch_bounds__(512)
void gemm_scores_kernel(const float* __restrict__ h,
                        const short* __restrict__ wt_hi, const short* __restrict__ wt_lo,
                        const float* __restrict__ a, short* __restrict__ gt,
                        float* __restrict__ s_l, float* __restrict__ s_r_t) {
  __shared__ float xbuf[4][64][8];
  const int bid = blockIdx.x;
  const int mb = bid >> 2;             // 64 m-tiles of 32 rows
  const int nb = bid & 3;              // 4 head-pairs
  const int w = threadIdx.x >> 6;
  const int l = threadIdx.x & 63;
  const int il = l & 15, q = l >> 4;
  const int wm = w >> 2;               // row half
  const int hp = (w >> 1) & 1;         // head within pair
  const int ks = w & 1;                // K half
  const int hh = nb * 2 + hp;
  const int rowb = mb * 32 + wm * 16;
  const int kb = ks * (IN_F / 2);

  const float* ahf = h + (rowb + il) * IN_F + kb;
  const short* bh0 = wt_hi + (hh * HF + il) * IN_F + kb;
  const short* bl0 = wt_lo + (hh * HF + il) * IN_F + kb;
  const short* bh1 = bh0 + 16 * IN_F;
  const short* bl1 = bl0 + 16 * IN_F;

  f32x4 acc0 = {0.f, 0.f, 0.f, 0.f};
  f32x4 acc1 = {0.f, 0.f, 0.f, 0.f};
  #pragma unroll 4
  for (int k0 = 0; k0 < IN_F / 2; k0 += 32) {
    const float4 av0 = *(const float4*)(ahf + k0 + 8 * q);
    const float4 av1 = *(const float4*)(ahf + k0 + 8 * q + 4);
    short8 a_h;
    a_h[0] = f2bf(av0.x); a_h[1] = f2bf(av0.y);
    a_h[2] = f2bf(av0.z); a_h[3] = f2bf(av0.w);
    a_h[4] = f2bf(av1.x); a_h[5] = f2bf(av1.y);
    a_h[6] = f2bf(av1.z); a_h[7] = f2bf(av1.w);
    const short8 b_h0 = *(const short8*)(bh0 + k0 + 8 * q);
    const short8 b_l0 = *(const short8*)(bl0 + k0 + 8 * q);
    const short8 b_h1 = *(const short8*)(bh1 + k0 + 8 * q);
    const short8 b_l1 = *(const short8*)(bl1 + k0 + 8 * q);
    acc0 = __builtin_amdgcn_mfma_f32_16x16x32_bf16(a_h, b_h0, acc0, 0, 0, 0);
    acc0 = __builtin_amdgcn_mfma_f32_16x16x32_bf16(a_h, b_l0, acc0, 0, 0, 0);
    acc1 = __builtin_amdgcn_mfma_f32_16x16x32_bf16(a_h, b_h1, acc1, 0, 0, 0);
    acc1 = __builtin_amdgcn_mfma_f32_16x16x32_bf16(a_h, b_l1, acc1, 0, 0, 0);
  }

  const int t = w >> 1;                // tile 0..3 (wm,hp)
  if (ks == 1) {
    *(f32x4*)&xbuf[t][l][0] = acc0;
    *(f32x4*)&xbuf[t][l][4] = acc1;
  }
  __syncthreads();
  if (ks == 1) return;
  {
    const f32x4 u0 = *(const f32x4*)&xbuf[t][l][0];
    const f32x4 u1 = *(const f32x4*)&xbuf[t][l][4];
    #pragma unroll
    for (int r = 0; r < 4; ++r) { acc0[r] += u0[r]; acc1[r] += u1[r]; }
  }

  // gt: D row = rowb + 4q + r, f = il / 16+il
  {
    short4v p0, p1;
    #pragma unroll
    for (int r = 0; r < 4; ++r) { p0[r] = f2bf(acc0[r]); p1[r] = f2bf(acc1[r]); }
    *(short4v*)(gt + (hh * HF + il) * N_NODES + rowb + 4 * q)      = p0;
    *(short4v*)(gt + (hh * HF + 16 + il) * N_NODES + rowb + 4 * q) = p1;
  }

  // scores, pre-scaled by log2(e)
  const float alv0 = a[il], alv1 = a[16 + il];
  const float arv0 = a[HF + il], arv1 = a[HF + 16 + il];
  float sl[4], sr[4];
  #pragma unroll
  for (int r = 0; r < 4; ++r) {
    sl[r] = acc0[r] * alv0 + acc1[r] * alv1;
    sr[r] = acc0[r] * arv0 + acc1[r] * arv1;
  }
  #pragma unroll
  for (int off = 8; off >= 1; off >>= 1) {
    #pragma unroll
    for (int r = 0; r < 4; ++r) {
      sl[r] += __shfl_xor(sl[r], off, 64);
      sr[r] += __shfl_xor(sr[r], off, 64);
    }
  }
  if (il == 0) {
    #pragma unroll
    for (int r = 0; r < 4; ++r) {
      const int node = rowb + 4 * q + r;
      s_l[node * NH + hh] = sl[r] * LOG2E;
      s_r_t[hh * N_NODES + node] = sr[r] * LOG2E;
    }
  }
}

// ---------------- Kernel 3: MFMA attention, 64-i blocks (2x gt reuse) ------
// 256 blocks (32 i-blocks of 64 rows x 8 heads) x 8 waves = 2 i-groups x
// 4 j-quarter waves (512 j each). Wave = 32 i rows (2 A-frags) sharing each
// gt B-pair. Per i-group, 4 j-partials merge in LDS; js=0 wave normalizes
// with the R12-proven shfl(tot, 4q+r) denom redistribution and writes out.
__global__ __launch_bounds__(512)
void attn_mfma_kernel(const unsigned* __restrict__ bits, const short* __restrict__ gt,
                      const float* __restrict__ s_l, const float* __restrict__ s_r_t,
                      float* __restrict__ out) {
  __shared__ float accbuf[2][3][64][16];
  __shared__ float dbuf[2][3][64][2];
  const int i0 = (blockIdx.x >> 3) * 64;
  const int hh = blockIdx.x & 7;
  const int w  = threadIdx.x >> 6;
  const int ig = w >> 2;                    // i-group (32 rows each)
  const int js = w & 3;                     // j-quarter wave
  const int l  = threadIdx.x & 63;
  const int il = l & 15;
  const int q  = l >> 4;
  const int ib = i0 + ig * 32;

  const float slv0 = s_l[(ib + il) * NH + hh];
  const float slv1 = s_l[(ib + 16 + il) * NH + hh];
  const unsigned* bitrow0 = bits + (ib + il) * 64;
  const unsigned* bitrow1 = bits + (ib + 16 + il) * 64;
  const float* srh = s_r_t + hh * N_NODES;
  const short* g0p = gt + (hh * HF + il) * N_NODES;
  const short* g1p = gt + (hh * HF + 16 + il) * N_NODES;

  f32x4 acc00 = {0.f,0.f,0.f,0.f};   // i-half 0, cols il
  f32x4 acc01 = {0.f,0.f,0.f,0.f};   // i-half 0, cols 16+il
  f32x4 acc10 = {0.f,0.f,0.f,0.f};   // i-half 1, cols il
  f32x4 acc11 = {0.f,0.f,0.f,0.f};   // i-half 1, cols 16+il
  float d0 = 0.f, d1 = 0.f;

  const int jbase = js * (N_NODES / 4);
  #pragma unroll 2
  for (int j0 = jbase; j0 < jbase + N_NODES / 4; j0 += 32) {
    const unsigned wq0 = bitrow0[j0 >> 5] >> (8 * q);
    const unsigned wq1 = bitrow1[j0 >> 5] >> (8 * q);
    const float4 sra = *(const float4*)(srh + j0 + 8 * q);
    const float4 srb = *(const float4*)(srh + j0 + 8 * q + 4);
    const float sr_[8] = {sra.x, sra.y, sra.z, sra.w, srb.x, srb.y, srb.z, srb.w};
    short8 af0, af1;
    #pragma unroll
    for (int r = 0; r < 8; ++r) {
      float e0 = slv0 + sr_[r];
      e0 = fmaxf(e0, 0.2f * e0);
      const float w0 = ((wq0 >> r) & 1u) ? fexp2(e0) : 0.f;
      const short wb0 = f2bf(w0);
      af0[r] = wb0;
      d0 += bf2f(wb0);
      float e1 = slv1 + sr_[r];
      e1 = fmaxf(e1, 0.2f * e1);
      const float w1 = ((wq1 >> r) & 1u) ? fexp2(e1) : 0.f;
      const short wb1 = f2bf(w1);
      af1[r] = wb1;
      d1 += bf2f(wb1);
    }
    const short8 b0 = *(const short8*)(g0p + j0 + 8 * q);
    const short8 b1 = *(const short8*)(g1p + j0 + 8 * q);
    acc00 = __builtin_amdgcn_mfma_f32_16x16x32_bf16(af0, b0, acc00, 0, 0, 0);
    acc01 = __builtin_amdgcn_mfma_f32_16x16x32_bf16(af0, b1, acc01, 0, 0, 0);
    acc10 = __builtin_amdgcn_mfma_f32_16x16x32_bf16(af1, b0, acc10, 0, 0, 0);
    acc11 = __builtin_amdgcn_mfma_f32_16x16x32_bf16(af1, b1, acc11, 0, 0, 0);
  }

  // reduce over q-groups: d0 -> node ib+il total (this j-range), d1 likewise
  d0 += __shfl_xor(d0, 16, 64);
  d0 += __shfl_xor(d0, 32, 64);
  d1 += __shfl_xor(d1, 16, 64);
  d1 += __shfl_xor(d1, 32, 64);

  if (js) {
    float* ab = &accbuf[ig][js - 1][l][0];
    *(f32x4*)(ab + 0)  = acc00;
    *(f32x4*)(ab + 4)  = acc01;
    *(f32x4*)(ab + 8)  = acc10;
    *(f32x4*)(ab + 12) = acc11;
    dbuf[ig][js - 1][l][0] = d0;
    dbuf[ig][js - 1][l][1] = d1;
  }
  __syncthreads();
  if (js) return;

  float t0 = d0, t1 = d1;
  #pragma unroll
  for (int s = 0; s < 3; ++s) {
    const float* ab = &accbuf[ig][s][l][0];
    const f32x4 u00 = *(const f32x4*)(ab + 0);
    const f32x4 u01 = *(const f32x4*)(ab + 4);
    const f32x4 u10 = *(const f32x4*)(ab + 8);
    const f32x4 u11 = *(const f32x4*)(ab + 12);
    #pragma unroll
    for (int r = 0; r < 4; ++r) {
      acc00[r] += u00[r]; acc01[r] += u01[r];
      acc10[r] += u10[r]; acc11[r] += u11[r];
    }
    t0 += dbuf[ig][s][l][0];
    t1 += dbuf[ig][s][l][1];
  }
  // t0 = node ib+il total denom; t1 = node ib+16+il. D rows are 4q+r ->
  // fetch the matching node's total from lane 4q+r (R12-proven pattern).
  #pragma unroll
  for (int r = 0; r < 4; ++r) {
    const int row0 = ib + 4 * q + r;
    const int row1 = ib + 16 + 4 * q + r;
    const float inv0 = 1.0f / __shfl(t0, 4 * q + r, 64);
    const float inv1 = 1.0f / __shfl(t1, 4 * q + r, 64);
    out[row0 * OUTF + hh * HF + il]      = acc00[r] * inv0;
    out[row0 * OUTF + hh * HF + 16 + il] = acc01[r] * inv0;
    out[row1 * OUTF + hh * HF + il]      = acc10[r] * inv1;
    out[row1 * OUTF + hh * HF + 16 + il] = acc11[r] * inv1;
  }
}

// ---------------------------------------------------------------------------
extern "C" void kernel_launch(void* const* d_in, const int* in_sizes, int n_in,
                              void* d_out, int out_size, void* d_ws, size_t ws_size,
                              hipStream_t stream) {
  const float* h   = (const float*)d_in[0];
  const int*   adj = (const int*)d_in[1];
  const float* W   = (const float*)d_in[2];
  const float* a   = (const float*)d_in[3];
  float* out = (float*)d_out;

  float* s_l   = (float*)d_ws;                       // 2048*8  (log2e-scaled)
  float* s_r_t = s_l + N_NODES * NH;                 // 8*2048  (log2e-scaled)
  unsigned* bits = (unsigned*)(s_r_t + NH * N_NODES);  // 2048*64 u32
  short* gt    = (short*)(bits + N_NODES * 64);      // 8*32*2048 bf16
  short* wt_hi = gt + NH * HF * N_NODES;             // 256*1024
  short* wt_lo = wt_hi + OUTF * IN_F;                // 256*1024

  prep_kernel<<<512, 256, 0, stream>>>(adj, W, wt_hi, wt_lo, bits);
  gemm_scores_kernel<<<256, 512, 0, stream>>>(h, wt_hi, wt_lo, a, gt, s_l, s_r_t);
  attn_mfma_kernel<<<256, 512, 0, stream>>>(bits, gt, s_l, s_r_t, out);
}

// Round 16
// 49.470 us; speedup vs baseline: 1.0718x; 1.0718x over previous
//
#include <hip/hip_runtime.h>
#include <hip/hip_bf16.h>
#include <math.h>

#define N_NODES 2048
#define IN_F    1024
#define NH      8
#define HF      32
#define OUTF    256   // NH*HF
#define LOG2E   1.4426950408889634f

typedef __attribute__((ext_vector_type(8))) short short8;
typedef __attribute__((ext_vector_type(4))) short short4v;
typedef __attribute__((ext_vector_type(4))) float f32x4;

__device__ __forceinline__ short f2bf(float x) {   // fp32 -> bf16 bits, RNE
  unsigned u = __float_as_uint(x);
  return (short)((u + 0x7FFFu + ((u >> 16) & 1u)) >> 16);
}
__device__ __forceinline__ float bf2f(short b) {
  return __uint_as_float(((unsigned)(unsigned short)b) << 16);
}
__device__ __forceinline__ float fexp2(float x) {  // native v_exp_f32 (2^x)
#if __has_builtin(__builtin_amdgcn_exp2f)
  return __builtin_amdgcn_exp2f(x);
#else
  return exp2f(x);
#endif
}

// ---------------- Kernel 1: prep — h->bf16, W->bf16 hi/lo (T), pack adj ----
__global__ __launch_bounds__(256)
void prep_kernel(const float* __restrict__ h, const int* __restrict__ adj,
                 const float* __restrict__ W, short* __restrict__ h_hi,
                 short* __restrict__ wt_hi, short* __restrict__ wt_lo,
                 unsigned* __restrict__ bits) {
  const int T = blockIdx.x * 256 + threadIdx.x;   // 0 .. 262143
  {
    const float4 v0 = *(const float4*)(h + T * 8);
    const float4 v1 = *(const float4*)(h + T * 8 + 4);
    const float x[8] = {v0.x, v0.y, v0.z, v0.w, v1.x, v1.y, v1.z, v1.w};
    short8 hi;
    #pragma unroll
    for (int j = 0; j < 8; ++j) hi[j] = f2bf(x[j]);
    *(short8*)(h_hi + T * 8) = hi;
  }
  if (T < (OUTF * IN_F / 8)) {
    // W: transpose + split. Lanes sweep n -> coalesced reads of W rows.
    const int kgrp = T >> 8, n = T & 255;      // 128 k-groups x 256 n
    #pragma unroll
    for (int j = 0; j < 8; ++j) {
      const float x = W[(kgrp * 8 + j) * OUTF + n];
      const short hb = f2bf(x);
      wt_hi[n * IN_F + kgrp * 8 + j] = hb;
      wt_lo[n * IN_F + kgrp * 8 + j] = f2bf(x - bf2f(hb));
    }
  }
  if (T < (N_NODES * 64)) {      // 131072 bit words
    const int4* p = (const int4*)(adj + (T >> 6) * N_NODES + (T & 63) * 32);
    unsigned wbits = 0;
    #pragma unroll
    for (int v = 0; v < 8; ++v) {
      const int4 x = p[v];
      wbits |= (x.x != 0 ? 1u : 0u) << (4 * v + 0);
      wbits |= (x.y != 0 ? 1u : 0u) << (4 * v + 1);
      wbits |= (x.z != 0 ? 1u : 0u) << (4 * v + 2);
      wbits |= (x.w != 0 ? 1u : 0u) << (4 * v + 3);
    }
    bits[T] = wbits;
  }
}

// ---------------- Kernel 2: g = h@W (MFMA, in-block K-split 2) + scores ----
// R12/R14-proven shape: 256 blocks x 8 waves. Wave = 16 rows x 1 head x
// K-half; K-halves merge through LDS. Emits gt + log2e-scaled scores.
__global__ __launch_bounds__(512)
void gemm_scores_kernel(const short* __restrict__ h_hi,
                        const short* __restrict__ wt_hi, const short* __restrict__ wt_lo,
                        const float* __restrict__ a, short* __restrict__ gt,
                        float* __restrict__ s_l, float* __restrict__ s_r_t) {
  __shared__ float xbuf[4][64][8];
  const int bid = blockIdx.x;
  const int mb = bid >> 2;             // 64 m-tiles of 32 rows
  const int nb = bid & 3;              // 4 head-pairs
  const int w = threadIdx.x >> 6;
  const int l = threadIdx.x & 63;
  const int il = l & 15, q = l >> 4;
  const int wm = w >> 2;               // row half
  const int hp = (w >> 1) & 1;         // head within pair
  const int ks = w & 1;                // K half
  const int hh = nb * 2 + hp;
  const int rowb = mb * 32 + wm * 16;
  const int kb = ks * (IN_F / 2);

  const short* ah  = h_hi + (rowb + il) * IN_F + kb;
  const short* bh0 = wt_hi + (hh * HF + il) * IN_F + kb;
  const short* bl0 = wt_lo + (hh * HF + il) * IN_F + kb;
  const short* bh1 = bh0 + 16 * IN_F;
  const short* bl1 = bl0 + 16 * IN_F;

  f32x4 acc0 = {0.f, 0.f, 0.f, 0.f};
  f32x4 acc1 = {0.f, 0.f, 0.f, 0.f};
  #pragma unroll 4
  for (int k0 = 0; k0 < IN_F / 2; k0 += 32) {
    const short8 a_h  = *(const short8*)(ah + k0 + 8 * q);
    const short8 b_h0 = *(const short8*)(bh0 + k0 + 8 * q);
    const short8 b_l0 = *(const short8*)(bl0 + k0 + 8 * q);
    const short8 b_h1 = *(const short8*)(bh1 + k0 + 8 * q);
    const short8 b_l1 = *(const short8*)(bl1 + k0 + 8 * q);
    acc0 = __builtin_amdgcn_mfma_f32_16x16x32_bf16(a_h, b_h0, acc0, 0, 0, 0);
    acc0 = __builtin_amdgcn_mfma_f32_16x16x32_bf16(a_h, b_l0, acc0, 0, 0, 0);
    acc1 = __builtin_amdgcn_mfma_f32_16x16x32_bf16(a_h, b_h1, acc1, 0, 0, 0);
    acc1 = __builtin_amdgcn_mfma_f32_16x16x32_bf16(a_h, b_l1, acc1, 0, 0, 0);
  }

  const int t = w >> 1;                // tile 0..3 (wm,hp)
  if (ks == 1) {
    *(f32x4*)&xbuf[t][l][0] = acc0;
    *(f32x4*)&xbuf[t][l][4] = acc1;
  }
  __syncthreads();
  if (ks == 1) return;
  {
    const f32x4 u0 = *(const f32x4*)&xbuf[t][l][0];
    const f32x4 u1 = *(const f32x4*)&xbuf[t][l][4];
    #pragma unroll
    for (int r = 0; r < 4; ++r) { acc0[r] += u0[r]; acc1[r] += u1[r]; }
  }

  // gt: D row = rowb + 4q + r, f = il / 16+il
  {
    short4v p0, p1;
    #pragma unroll
    for (int r = 0; r < 4; ++r) { p0[r] = f2bf(acc0[r]); p1[r] = f2bf(acc1[r]); }
    *(short4v*)(gt + (hh * HF + il) * N_NODES + rowb + 4 * q)      = p0;
    *(short4v*)(gt + (hh * HF + 16 + il) * N_NODES + rowb + 4 * q) = p1;
  }

  // scores, pre-scaled by log2(e)
  const float alv0 = a[il], alv1 = a[16 + il];
  const float arv0 = a[HF + il], arv1 = a[HF + 16 + il];
  float sl[4], sr[4];
  #pragma unroll
  for (int r = 0; r < 4; ++r) {
    sl[r] = acc0[r] * alv0 + acc1[r] * alv1;
    sr[r] = acc0[r] * arv0 + acc1[r] * arv1;
  }
  #pragma unroll
  for (int off = 8; off >= 1; off >>= 1) {
    #pragma unroll
    for (int r = 0; r < 4; ++r) {
      sl[r] += __shfl_xor(sl[r], off, 64);
      sr[r] += __shfl_xor(sr[r], off, 64);
    }
  }
  if (il == 0) {
    #pragma unroll
    for (int r = 0; r < 4; ++r) {
      const int node = rowb + 4 * q + r;
      s_l[node * NH + hh] = sl[r] * LOG2E;
      s_r_t[hh * N_NODES + node] = sr[r] * LOG2E;
    }
  }
}

// ---------------- Kernel 3: MFMA attention, 32-i waves, ones-MFMA denom ----
// R14-proven shape: 512 blocks (64 i-blocks of 32 rows x 8 heads) x 8
// j-eighth waves (256 j each). ONE CHANGE vs R14: the denominator is
// computed by an extra MFMA with an all-ones B-fragment -> dn[r] is the
// denom of row 4q+r directly (fp32, layout-aligned). No bf2f chain, no
// shfl_xor reduction, no epilogue shfl redistribution.
__global__ __launch_bounds__(512)
void attn_mfma_kernel(const unsigned* __restrict__ bits, const short* __restrict__ gt,
                      const float* __restrict__ s_l, const float* __restrict__ s_r_t,
                      float* __restrict__ out) {
  __shared__ float accbuf[7][64][16];
  __shared__ float dnbuf[7][64][8];
  const int i0 = (blockIdx.x >> 3) * 32;
  const int hh = blockIdx.x & 7;
  const int js = threadIdx.x >> 6;          // j-split wave 0..7
  const int l  = threadIdx.x & 63;
  const int il = l & 15;
  const int q  = l >> 4;

  const float slv0 = s_l[(i0 + il) * NH + hh];
  const float slv1 = s_l[(i0 + 16 + il) * NH + hh];
  const unsigned* bitrow0 = bits + (i0 + il) * 64;
  const unsigned* bitrow1 = bits + (i0 + 16 + il) * 64;
  const float* srh = s_r_t + hh * N_NODES;
  const short* g0p = gt + (hh * HF + il) * N_NODES;
  const short* g1p = gt + (hh * HF + 16 + il) * N_NODES;

  const short one_bf = (short)0x3F80;        // bf16 1.0
  const short8 ones = {one_bf, one_bf, one_bf, one_bf,
                       one_bf, one_bf, one_bf, one_bf};

  f32x4 acc00 = {0.f,0.f,0.f,0.f};   // i-half 0, cols il
  f32x4 acc01 = {0.f,0.f,0.f,0.f};   // i-half 0, cols 16+il
  f32x4 acc10 = {0.f,0.f,0.f,0.f};   // i-half 1, cols il
  f32x4 acc11 = {0.f,0.f,0.f,0.f};   // i-half 1, cols 16+il
  f32x4 dn0   = {0.f,0.f,0.f,0.f};   // dn0[r] = denom of node i0+4q+r
  f32x4 dn1   = {0.f,0.f,0.f,0.f};   // dn1[r] = denom of node i0+16+4q+r

  const int jbase = js * (N_NODES / 8);
  #pragma unroll 2
  for (int j0 = jbase; j0 < jbase + N_NODES / 8; j0 += 32) {
    const unsigned wq0 = bitrow0[j0 >> 5] >> (8 * q);
    const unsigned wq1 = bitrow1[j0 >> 5] >> (8 * q);
    const float4 sra = *(const float4*)(srh + j0 + 8 * q);
    const float4 srb = *(const float4*)(srh + j0 + 8 * q + 4);
    const float sr_[8] = {sra.x, sra.y, sra.z, sra.w, srb.x, srb.y, srb.z, srb.w};
    short8 af0, af1;
    #pragma unroll
    for (int r = 0; r < 8; ++r) {
      float e0 = slv0 + sr_[r];
      e0 = fmaxf(e0, 0.2f * e0);
      const float w0 = ((wq0 >> r) & 1u) ? fexp2(e0) : 0.f;
      af0[r] = f2bf(w0);
      float e1 = slv1 + sr_[r];
      e1 = fmaxf(e1, 0.2f * e1);
      const float w1 = ((wq1 >> r) & 1u) ? fexp2(e1) : 0.f;
      af1[r] = f2bf(w1);
    }
    const short8 b0 = *(const short8*)(g0p + j0 + 8 * q);
    const short8 b1 = *(const short8*)(g1p + j0 + 8 * q);
    acc00 = __builtin_amdgcn_mfma_f32_16x16x32_bf16(af0, b0, acc00, 0, 0, 0);
    acc01 = __builtin_amdgcn_mfma_f32_16x16x32_bf16(af0, b1, acc01, 0, 0, 0);
    acc10 = __builtin_amdgcn_mfma_f32_16x16x32_bf16(af1, b0, acc10, 0, 0, 0);
    acc11 = __builtin_amdgcn_mfma_f32_16x16x32_bf16(af1, b1, acc11, 0, 0, 0);
    dn0   = __builtin_amdgcn_mfma_f32_16x16x32_bf16(af0, ones, dn0, 0, 0, 0);
    dn1   = __builtin_amdgcn_mfma_f32_16x16x32_bf16(af1, ones, dn1, 0, 0, 0);
  }

  if (js) {
    float* ab = &accbuf[js - 1][l][0];
    *(f32x4*)(ab + 0)  = acc00;
    *(f32x4*)(ab + 4)  = acc01;
    *(f32x4*)(ab + 8)  = acc10;
    *(f32x4*)(ab + 12) = acc11;
    float* db = &dnbuf[js - 1][l][0];
    *(f32x4*)(db + 0) = dn0;
    *(f32x4*)(db + 4) = dn1;
  }
  __syncthreads();
  if (js) return;

  #pragma unroll
  for (int s = 0; s < 7; ++s) {
    const float* ab = &accbuf[s][l][0];
    const f32x4 u00 = *(const f32x4*)(ab + 0);
    const f32x4 u01 = *(const f32x4*)(ab + 4);
    const f32x4 u10 = *(const f32x4*)(ab + 8);
    const f32x4 u11 = *(const f32x4*)(ab + 12);
    const float* db = &dnbuf[s][l][0];
    const f32x4 v0 = *(const f32x4*)(db + 0);
    const f32x4 v1 = *(const f32x4*)(db + 4);
    #pragma unroll
    for (int r = 0; r < 4; ++r) {
      acc00[r] += u00[r]; acc01[r] += u01[r];
      acc10[r] += u10[r]; acc11[r] += u11[r];
      dn0[r] += v0[r];    dn1[r] += v1[r];
    }
  }
  // dn0[r]/dn1[r] are the denominators for exactly the rows this lane holds.
  #pragma unroll
  for (int r = 0; r < 4; ++r) {
    const int row0 = i0 + 4 * q + r;
    const int row1 = i0 + 16 + 4 * q + r;
    const float inv0 = 1.0f / dn0[r];
    const float inv1 = 1.0f / dn1[r];
    out[row0 * OUTF + hh * HF + il]      = acc00[r] * inv0;
    out[row0 * OUTF + hh * HF + 16 + il] = acc01[r] * inv0;
    out[row1 * OUTF + hh * HF + il]      = acc10[r] * inv1;
    out[row1 * OUTF + hh * HF + 16 + il] = acc11[r] * inv1;
  }
}

// ---------------------------------------------------------------------------
extern "C" void kernel_launch(void* const* d_in, const int* in_sizes, int n_in,
                              void* d_out, int out_size, void* d_ws, size_t ws_size,
                              hipStream_t stream) {
  const float* h   = (const float*)d_in[0];
  const int*   adj = (const int*)d_in[1];
  const float* W   = (const float*)d_in[2];
  const float* a   = (const float*)d_in[3];
  float* out = (float*)d_out;

  float* s_l   = (float*)d_ws;                       // 2048*8  (log2e-scaled)
  float* s_r_t = s_l + N_NODES * NH;                 // 8*2048  (log2e-scaled)
  unsigned* bits = (unsigned*)(s_r_t + NH * N_NODES);  // 2048*64 u32
  short* gt    = (short*)(bits + N_NODES * 64);      // 8*32*2048 bf16
  short* h_hi  = gt + NH * HF * N_NODES;             // 2048*1024
  short* wt_hi = h_hi + N_NODES * IN_F;              // 256*1024
  short* wt_lo = wt_hi + OUTF * IN_F;                // 256*1024

  prep_kernel<<<1024, 256, 0, stream>>>(h, adj, W, h_hi, wt_hi, wt_lo, bits);
  gemm_scores_kernel<<<256, 512, 0, stream>>>(h_hi, wt_hi, wt_lo, a, gt, s_l, s_r_t);
  attn_mfma_kernel<<<512, 512, 0, stream>>>(bits, gt, s_l, s_r_t, out);
}

// Round 17
// 49.288 us; speedup vs baseline: 1.0757x; 1.0037x over previous
//
#include <hip/hip_runtime.h>
#include <hip/hip_bf16.h>
#include <math.h>

#define N_NODES 2048
#define IN_F    1024
#define NH      8
#define HF      32
#define OUTF    256   // NH*HF
#define LOG2E   1.4426950408889634f

typedef __attribute__((ext_vector_type(8))) short short8;
typedef __attribute__((ext_vector_type(4))) short short4v;
typedef __attribute__((ext_vector_type(4))) float f32x4;

__device__ __forceinline__ short f2bf(float x) {   // fp32 -> bf16 bits, RNE
  unsigned u = __float_as_uint(x);
  return (short)((u + 0x7FFFu + ((u >> 16) & 1u)) >> 16);
}
__device__ __forceinline__ float bf2f(short b) {
  return __uint_as_float(((unsigned)(unsigned short)b) << 16);
}
__device__ __forceinline__ short f2bf_hw(float x) { // compiler cast -> v_cvt_pk
  union { __hip_bfloat16 b; short s; } cv;
  cv.b = __float2bfloat16(x);
  return cv.s;
}
__device__ __forceinline__ float fexp2(float x) {  // native v_exp_f32 (2^x)
#if __has_builtin(__builtin_amdgcn_exp2f)
  return __builtin_amdgcn_exp2f(x);
#else
  return exp2f(x);
#endif
}

// ---------------- Kernel 1: prep — h->bf16, W->bf16 hi/lo (T), pack adj ----
__global__ __launch_bounds__(256)
void prep_kernel(const float* __restrict__ h, const int* __restrict__ adj,
                 const float* __restrict__ W, short* __restrict__ h_hi,
                 short* __restrict__ wt_hi, short* __restrict__ wt_lo,
                 unsigned* __restrict__ bits) {
  const int T = blockIdx.x * 256 + threadIdx.x;   // 0 .. 262143
  {
    const float4 v0 = *(const float4*)(h + T * 8);
    const float4 v1 = *(const float4*)(h + T * 8 + 4);
    const float x[8] = {v0.x, v0.y, v0.z, v0.w, v1.x, v1.y, v1.z, v1.w};
    short8 hi;
    #pragma unroll
    for (int j = 0; j < 8; ++j) hi[j] = f2bf(x[j]);
    *(short8*)(h_hi + T * 8) = hi;
  }
  if (T < (OUTF * IN_F / 8)) {
    // W: transpose + split. Lanes sweep n -> coalesced reads of W rows.
    const int kgrp = T >> 8, n = T & 255;      // 128 k-groups x 256 n
    #pragma unroll
    for (int j = 0; j < 8; ++j) {
      const float x = W[(kgrp * 8 + j) * OUTF + n];
      const short hb = f2bf(x);
      wt_hi[n * IN_F + kgrp * 8 + j] = hb;
      wt_lo[n * IN_F + kgrp * 8 + j] = f2bf(x - bf2f(hb));
    }
  }
  if (T < (N_NODES * 64)) {      // 131072 bit words
    const int4* p = (const int4*)(adj + (T >> 6) * N_NODES + (T & 63) * 32);
    unsigned wbits = 0;
    #pragma unroll
    for (int v = 0; v < 8; ++v) {
      const int4 x = p[v];
      wbits |= (x.x != 0 ? 1u : 0u) << (4 * v + 0);
      wbits |= (x.y != 0 ? 1u : 0u) << (4 * v + 1);
      wbits |= (x.z != 0 ? 1u : 0u) << (4 * v + 2);
      wbits |= (x.w != 0 ? 1u : 0u) << (4 * v + 3);
    }
    bits[T] = wbits;
  }
}

// ---------------- Kernel 2: g = h@W (MFMA, in-block K-split 2) + scores ----
// R12/R14-proven shape: 256 blocks x 8 waves. Wave = 16 rows x 1 head x
// K-half; K-halves merge through LDS. Emits gt + log2e-scaled scores.
__global__ __launch_bounds__(512)
void gemm_scores_kernel(const short* __restrict__ h_hi,
                        const short* __restrict__ wt_hi, const short* __restrict__ wt_lo,
                        const float* __restrict__ a, short* __restrict__ gt,
                        float* __restrict__ s_l, float* __restrict__ s_r_t) {
  __shared__ float xbuf[4][64][8];
  const int bid = blockIdx.x;
  const int mb = bid >> 2;             // 64 m-tiles of 32 rows
  const int nb = bid & 3;              // 4 head-pairs
  const int w = threadIdx.x >> 6;
  const int l = threadIdx.x & 63;
  const int il = l & 15, q = l >> 4;
  const int wm = w >> 2;               // row half
  const int hp = (w >> 1) & 1;         // head within pair
  const int ks = w & 1;                // K half
  const int hh = nb * 2 + hp;
  const int rowb = mb * 32 + wm * 16;
  const int kb = ks * (IN_F / 2);

  const short* ah  = h_hi + (rowb + il) * IN_F + kb;
  const short* bh0 = wt_hi + (hh * HF + il) * IN_F + kb;
  const short* bl0 = wt_lo + (hh * HF + il) * IN_F + kb;
  const short* bh1 = bh0 + 16 * IN_F;
  const short* bl1 = bl0 + 16 * IN_F;

  f32x4 acc0 = {0.f, 0.f, 0.f, 0.f};
  f32x4 acc1 = {0.f, 0.f, 0.f, 0.f};
  #pragma unroll 4
  for (int k0 = 0; k0 < IN_F / 2; k0 += 32) {
    const short8 a_h  = *(const short8*)(ah + k0 + 8 * q);
    const short8 b_h0 = *(const short8*)(bh0 + k0 + 8 * q);
    const short8 b_l0 = *(const short8*)(bl0 + k0 + 8 * q);
    const short8 b_h1 = *(const short8*)(bh1 + k0 + 8 * q);
    const short8 b_l1 = *(const short8*)(bl1 + k0 + 8 * q);
    acc0 = __builtin_amdgcn_mfma_f32_16x16x32_bf16(a_h, b_h0, acc0, 0, 0, 0);
    acc0 = __builtin_amdgcn_mfma_f32_16x16x32_bf16(a_h, b_l0, acc0, 0, 0, 0);
    acc1 = __builtin_amdgcn_mfma_f32_16x16x32_bf16(a_h, b_h1, acc1, 0, 0, 0);
    acc1 = __builtin_amdgcn_mfma_f32_16x16x32_bf16(a_h, b_l1, acc1, 0, 0, 0);
  }

  const int t = w >> 1;                // tile 0..3 (wm,hp)
  if (ks == 1) {
    *(f32x4*)&xbuf[t][l][0] = acc0;
    *(f32x4*)&xbuf[t][l][4] = acc1;
  }
  __syncthreads();
  if (ks == 1) return;
  {
    const f32x4 u0 = *(const f32x4*)&xbuf[t][l][0];
    const f32x4 u1 = *(const f32x4*)&xbuf[t][l][4];
    #pragma unroll
    for (int r = 0; r < 4; ++r) { acc0[r] += u0[r]; acc1[r] += u1[r]; }
  }

  // gt: D row = rowb + 4q + r, f = il / 16+il
  {
    short4v p0, p1;
    #pragma unroll
    for (int r = 0; r < 4; ++r) { p0[r] = f2bf(acc0[r]); p1[r] = f2bf(acc1[r]); }
    *(short4v*)(gt + (hh * HF + il) * N_NODES + rowb + 4 * q)      = p0;
    *(short4v*)(gt + (hh * HF + 16 + il) * N_NODES + rowb + 4 * q) = p1;
  }

  // scores, pre-scaled by log2(e)
  const float alv0 = a[il], alv1 = a[16 + il];
  const float arv0 = a[HF + il], arv1 = a[HF + 16 + il];
  float sl[4], sr[4];
  #pragma unroll
  for (int r = 0; r < 4; ++r) {
    sl[r] = acc0[r] * alv0 + acc1[r] * alv1;
    sr[r] = acc0[r] * arv0 + acc1[r] * arv1;
  }
  #pragma unroll
  for (int off = 8; off >= 1; off >>= 1) {
    #pragma unroll
    for (int r = 0; r < 4; ++r) {
      sl[r] += __shfl_xor(sl[r], off, 64);
      sr[r] += __shfl_xor(sr[r], off, 64);
    }
  }
  if (il == 0) {
    #pragma unroll
    for (int r = 0; r < 4; ++r) {
      const int node = rowb + 4 * q + r;
      s_l[node * NH + hh] = sl[r] * LOG2E;
      s_r_t[hh * N_NODES + node] = sr[r] * LOG2E;
    }
  }
}

// ---------------- Kernel 3: MFMA attention, ones-MFMA denom, hw cvt --------
// R16-proven shape: 512 blocks (64 i-blocks of 32 rows x 8 heads) x 8
// j-eighth waves. ONE CHANGE vs R16: A-fragment bf16 conversion uses the
// compiler-lowered __float2bfloat16 cast (fuses to v_cvt_pk_bf16_f32) in
// place of the 3-op bit-twiddle. Same RNE rounding -> bit-identical output
// (verified R10 vs R11: absmax invariant under this swap).
__global__ __launch_bounds__(512)
void attn_mfma_kernel(const unsigned* __restrict__ bits, const short* __restrict__ gt,
                      const float* __restrict__ s_l, const float* __restrict__ s_r_t,
                      float* __restrict__ out) {
  __shared__ float accbuf[7][64][16];
  __shared__ float dnbuf[7][64][8];
  const int i0 = (blockIdx.x >> 3) * 32;
  const int hh = blockIdx.x & 7;
  const int js = threadIdx.x >> 6;          // j-split wave 0..7
  const int l  = threadIdx.x & 63;
  const int il = l & 15;
  const int q  = l >> 4;

  const float slv0 = s_l[(i0 + il) * NH + hh];
  const float slv1 = s_l[(i0 + 16 + il) * NH + hh];
  const unsigned* bitrow0 = bits + (i0 + il) * 64;
  const unsigned* bitrow1 = bits + (i0 + 16 + il) * 64;
  const float* srh = s_r_t + hh * N_NODES;
  const short* g0p = gt + (hh * HF + il) * N_NODES;
  const short* g1p = gt + (hh * HF + 16 + il) * N_NODES;

  const short one_bf = (short)0x3F80;        // bf16 1.0
  const short8 ones = {one_bf, one_bf, one_bf, one_bf,
                       one_bf, one_bf, one_bf, one_bf};

  f32x4 acc00 = {0.f,0.f,0.f,0.f};   // i-half 0, cols il
  f32x4 acc01 = {0.f,0.f,0.f,0.f};   // i-half 0, cols 16+il
  f32x4 acc10 = {0.f,0.f,0.f,0.f};   // i-half 1, cols il
  f32x4 acc11 = {0.f,0.f,0.f,0.f};   // i-half 1, cols 16+il
  f32x4 dn0   = {0.f,0.f,0.f,0.f};   // dn0[r] = denom of node i0+4q+r
  f32x4 dn1   = {0.f,0.f,0.f,0.f};   // dn1[r] = denom of node i0+16+4q+r

  const int jbase = js * (N_NODES / 8);
  #pragma unroll 2
  for (int j0 = jbase; j0 < jbase + N_NODES / 8; j0 += 32) {
    const unsigned wq0 = bitrow0[j0 >> 5] >> (8 * q);
    const unsigned wq1 = bitrow1[j0 >> 5] >> (8 * q);
    const float4 sra = *(const float4*)(srh + j0 + 8 * q);
    const float4 srb = *(const float4*)(srh + j0 + 8 * q + 4);
    const float sr_[8] = {sra.x, sra.y, sra.z, sra.w, srb.x, srb.y, srb.z, srb.w};
    short8 af0, af1;
    #pragma unroll
    for (int r = 0; r < 8; ++r) {
      float e0 = slv0 + sr_[r];
      e0 = fmaxf(e0, 0.2f * e0);
      const float w0 = ((wq0 >> r) & 1u) ? fexp2(e0) : 0.f;
      af0[r] = f2bf_hw(w0);
      float e1 = slv1 + sr_[r];
      e1 = fmaxf(e1, 0.2f * e1);
      const float w1 = ((wq1 >> r) & 1u) ? fexp2(e1) : 0.f;
      af1[r] = f2bf_hw(w1);
    }
    const short8 b0 = *(const short8*)(g0p + j0 + 8 * q);
    const short8 b1 = *(const short8*)(g1p + j0 + 8 * q);
    acc00 = __builtin_amdgcn_mfma_f32_16x16x32_bf16(af0, b0, acc00, 0, 0, 0);
    acc01 = __builtin_amdgcn_mfma_f32_16x16x32_bf16(af0, b1, acc01, 0, 0, 0);
    acc10 = __builtin_amdgcn_mfma_f32_16x16x32_bf16(af1, b0, acc10, 0, 0, 0);
    acc11 = __builtin_amdgcn_mfma_f32_16x16x32_bf16(af1, b1, acc11, 0, 0, 0);
    dn0   = __builtin_amdgcn_mfma_f32_16x16x32_bf16(af0, ones, dn0, 0, 0, 0);
    dn1   = __builtin_amdgcn_mfma_f32_16x16x32_bf16(af1, ones, dn1, 0, 0, 0);
  }

  if (js) {
    float* ab = &accbuf[js - 1][l][0];
    *(f32x4*)(ab + 0)  = acc00;
    *(f32x4*)(ab + 4)  = acc01;
    *(f32x4*)(ab + 8)  = acc10;
    *(f32x4*)(ab + 12) = acc11;
    float* db = &dnbuf[js - 1][l][0];
    *(f32x4*)(db + 0) = dn0;
    *(f32x4*)(db + 4) = dn1;
  }
  __syncthreads();
  if (js) return;

  #pragma unroll
  for (int s = 0; s < 7; ++s) {
    const float* ab = &accbuf[s][l][0];
    const f32x4 u00 = *(const f32x4*)(ab + 0);
    const f32x4 u01 = *(const f32x4*)(ab + 4);
    const f32x4 u10 = *(const f32x4*)(ab + 8);
    const f32x4 u11 = *(const f32x4*)(ab + 12);
    const float* db = &dnbuf[s][l][0];
    const f32x4 v0 = *(const f32x4*)(db + 0);
    const f32x4 v1 = *(const f32x4*)(db + 4);
    #pragma unroll
    for (int r = 0; r < 4; ++r) {
      acc00[r] += u00[r]; acc01[r] += u01[r];
      acc10[r] += u10[r]; acc11[r] += u11[r];
      dn0[r] += v0[r];    dn1[r] += v1[r];
    }
  }
  // dn0[r]/dn1[r] are the denominators for exactly the rows this lane holds.
  #pragma unroll
  for (int r = 0; r < 4; ++r) {
    const int row0 = i0 + 4 * q + r;
    const int row1 = i0 + 16 + 4 * q + r;
    const float inv0 = 1.0f / dn0[r];
    const float inv1 = 1.0f / dn1[r];
    out[row0 * OUTF + hh * HF + il]      = acc00[r] * inv0;
    out[row0 * OUTF + hh * HF + 16 + il] = acc01[r] * inv0;
    out[row1 * OUTF + hh * HF + il]      = acc10[r] * inv1;
    out[row1 * OUTF + hh * HF + 16 + il] = acc11[r] * inv1;
  }
}

// ---------------------------------------------------------------------------
extern "C" void kernel_launch(void* const* d_in, const int* in_sizes, int n_in,
                              void* d_out, int out_size, void* d_ws, size_t ws_size,
                              hipStream_t stream) {
  const float* h   = (const float*)d_in[0];
  const int*   adj = (const int*)d_in[1];
  const float* W   = (const float*)d_in[2];
  const float* a   = (const float*)d_in[3];
  float* out = (float*)d_out;

  float* s_l   = (float*)d_ws;                       // 2048*8  (log2e-scaled)
  float* s_r_t = s_l + N_NODES * NH;                 // 8*2048  (log2e-scaled)
  unsigned* bits = (unsigned*)(s_r_t + NH * N_NODES);  // 2048*64 u32
  short* gt    = (short*)(bits + N_NODES * 64);      // 8*32*2048 bf16
  short* h_hi  = gt + NH * HF * N_NODES;             // 2048*1024
  short* wt_hi = h_hi + N_NODES * IN_F;              // 256*1024
  short* wt_lo = wt_hi + OUTF * IN_F;                // 256*1024

  prep_kernel<<<1024, 256, 0, stream>>>(h, adj, W, h_hi, wt_hi, wt_lo, bits);
  gemm_scores_kernel<<<256, 512, 0, stream>>>(h_hi, wt_hi, wt_lo, a, gt, s_l, s_r_t);
  attn_mfma_kernel<<<512, 512, 0, stream>>>(bits, gt, s_l, s_r_t, out);
}